// Round 3
// baseline (320.026 us; speedup 1.0000x reference)
//
#include <hip/hip_runtime.h>

// SKA: per-pixel dynamic depthwise 5x5 conv
// x: [B=8, C=256, H=64, W=64] f32
// w: [B=8, G=8, K2=25, H=64, W=64] f32
// out[b,c,h,w] = sum_k x[b,c,h+k/5-2,w+k%5-2] * w[b,g,k,h,w], g = c/32
//
// Design C (round 3): fix latency exposure seen in round 2 (all pipes <16%).
// - csplit=4 (NCH=8): grid 1024 -> 4 blocks/CU, occupancy doubles.
// - rotating 3-row load window: 9 loads in flight before first FMA,
//   remaining 2 row-loads interleaved between FMA rows (was: 3-load
//   serialized chunks, ~24 in-flight loads/CU vs ~25 needed for latency).
// - __launch_bounds__(256,3): VGPR cap ~170; wk(100)+window(36)+misc ~160.

#define B_ 8
#define C_ 256
#define G_ 8
#define CG_ 32
#define H_ 64
#define W_ 64
#define K2_ 25
#define HW_ (H_ * W_)
#define NCH 8    // channels per block (CG_/4)
#define ROWS 16  // output rows per block band

__device__ __forceinline__ void load_row(float* xr, const float* rp, int c0m,
                                         int wcol, int c2m) {
  *(float4*)&xr[0] = *(const float4*)(rp + c0m);
  *(float4*)&xr[4] = *(const float4*)(rp + wcol);
  *(float4*)&xr[8] = *(const float4*)(rp + c2m);
}

__device__ __forceinline__ void fma_row(float* acc, const float* xr,
                                        const float (*wk)[4], int di) {
#pragma unroll
  for (int dj = 0; dj < 5; ++dj) {
    const int k = di * 5 + dj;
#pragma unroll
    for (int t = 0; t < 4; ++t) {
      acc[t] = fmaf(xr[2 + t + dj], wk[k][t], acc[t]);
    }
  }
}

__global__ __launch_bounds__(256, 3) void ska_kernel(
    const float* __restrict__ x, const float* __restrict__ w,
    float* __restrict__ out) {
  const int tid = threadIdx.x;
  const int j = tid & 15;   // column quad: cols 4j..4j+3
  const int r = tid >> 4;   // row within band (0..15)
  const int blk = blockIdx.x;  // 1024 blocks
  const int chunk = blk & 3;          // channel chunk (8 channels each)
  const int band = (blk >> 2) & 3;    // 16-row band
  const int g = (blk >> 4) & 7;
  const int b = blk >> 7;
  const int h = band * ROWS + r;
  const int wcol = j * 4;

  // ---- 25 per-pixel weight quads, OOB masks folded in (branch-free) ----
  float wk[K2_][4];
  const float* wb =
      w + (size_t)(b * G_ + g) * K2_ * HW_ + (size_t)h * W_ + wcol;
#pragma unroll
  for (int k = 0; k < K2_; ++k) {
    const int di = k / 5 - 2;
    const int dj = k % 5 - 2;
    const int hh = h + di;
    const bool rowok = (unsigned)hh < (unsigned)H_;
    const float4 wv = *(const float4*)(wb + (size_t)k * HW_);
#pragma unroll
    for (int t = 0; t < 4; ++t) {
      const int cc = wcol + t + dj;
      const bool ok = rowok && ((unsigned)cc < (unsigned)W_);
      wk[k][t] = ok ? ((const float*)&wv)[t] : 0.0f;
    }
  }

  // ---- clamped row offsets; clamped aligned column bases ----
  int rowoff[5];
#pragma unroll
  for (int di = 0; di < 5; ++di) {
    int hh = h + di - 2;
    hh = min(max(hh, 0), H_ - 1);
    rowoff[di] = hh * W_;
  }
  const int c0m = max(wcol - 4, 0);       // garbage at j=0 meets wk==0
  const int c2m = min(wcol + 4, W_ - 4);  // garbage at j=15 meets wk==0

  const size_t chan0 = (size_t)(b * C_ + g * CG_ + chunk * NCH) * HW_;
  const float* xc = x + chan0;
  float* ob = out + chan0 + (size_t)h * W_ + wcol;

  for (int c = 0; c < NCH; ++c) {
    const float* xp = xc + (size_t)c * HW_;
    float acc[4] = {0.f, 0.f, 0.f, 0.f};
    float x0[12], x1[12], x2[12];  // rotating 3-row window
    load_row(x0, xp + rowoff[0], c0m, wcol, c2m);
    load_row(x1, xp + rowoff[1], c0m, wcol, c2m);
    load_row(x2, xp + rowoff[2], c0m, wcol, c2m);
    fma_row(acc, x0, wk, 0);
    load_row(x0, xp + rowoff[3], c0m, wcol, c2m);
    fma_row(acc, x1, wk, 1);
    load_row(x1, xp + rowoff[4], c0m, wcol, c2m);
    fma_row(acc, x2, wk, 2);
    fma_row(acc, x0, wk, 3);
    fma_row(acc, x1, wk, 4);
    *(float4*)(ob + (size_t)c * HW_) =
        make_float4(acc[0], acc[1], acc[2], acc[3]);
  }
}

extern "C" void kernel_launch(void* const* d_in, const int* in_sizes, int n_in,
                              void* d_out, int out_size, void* d_ws,
                              size_t ws_size, hipStream_t stream) {
  const float* x = (const float*)d_in[0];
  const float* w = (const float*)d_in[1];
  float* out = (float*)d_out;
  // grid: B*G * 4 bands * 4 channel-chunks = 1024 blocks of 256 threads
  ska_kernel<<<dim3(1024), dim3(256), 0, stream>>>(x, w, out);
}

// Round 4
// 135.735 us; speedup vs baseline: 2.3577x; 2.3577x over previous
//
#include <hip/hip_runtime.h>

// SKA: per-pixel dynamic depthwise 5x5 conv
// x: [B=8, C=256, H=64, W=64] f32
// w: [B=8, G=8, K2=25, H=64, W=64] f32
// out[b,c,h,w] = sum_k x[b,c,h+k/5-2,w+k%5-2] * w[b,g,k,h,w], g = c/32
//
// Design D (round 4): round-2 structure EXACTLY (124 VGPR, zero spill;
// round 3's helper-fn restructure + (256,3) cap spilled to scratch:
// VGPR 84, WRITE_SIZE 210 MB -> 248 us). Only change vs round 2:
// NCH 16 -> 8, grid 512 -> 1024 blocks, so 4 blocks/CU x 4 waves = 16
// waves/CU (round 2 was grid-limited to 8 waves/CU, all pipes <16% busy).

#define B_ 8
#define C_ 256
#define G_ 8
#define CG_ 32
#define H_ 64
#define W_ 64
#define K2_ 25
#define HW_ (H_ * W_)
#define NCH 8    // channels per block (CG_/4)
#define ROWS 16  // output rows per block band

__global__ __launch_bounds__(256, 2) void ska_kernel(
    const float* __restrict__ x, const float* __restrict__ w,
    float* __restrict__ out) {
  const int tid = threadIdx.x;
  const int j = tid & 15;   // column quad index: cols 4j..4j+3
  const int r = tid >> 4;   // row within band
  const int blk = blockIdx.x;  // 1024 blocks
  const int chunk = blk & 3;        // channel chunk (8 channels)
  const int band = (blk >> 2) & 3;  // 16-row band
  const int g = (blk >> 4) & 7;
  const int b = blk >> 7;
  const int h = band * ROWS + r;
  const int wcol = j * 4;

  // ---- load 25 per-pixel weight quads once; fold OOB masks in ----
  float wk[K2_][4];
  const float* wb =
      w + (size_t)(b * G_ + g) * K2_ * HW_ + (size_t)h * W_ + wcol;
#pragma unroll
  for (int k = 0; k < K2_; ++k) {
    const int di = k / 5 - 2;
    const int dj = k % 5 - 2;
    const int hh = h + di;
    const bool rowok = (unsigned)hh < (unsigned)H_;
    const float4 wv = *(const float4*)(wb + (size_t)k * HW_);
#pragma unroll
    for (int t = 0; t < 4; ++t) {
      const int cc = wcol + t + dj;
      const bool ok = rowok && ((unsigned)cc < (unsigned)W_);
      wk[k][t] = ok ? ((const float*)&wv)[t] : 0.0f;
    }
  }

  // ---- clamped row offsets and column bases for the 3 f4 loads ----
  int rowoff[5];
#pragma unroll
  for (int di = 0; di < 5; ++di) {
    int hh = h + di - 2;
    hh = min(max(hh, 0), H_ - 1);
    rowoff[di] = hh * W_;
  }
  const int c0m = max(wcol - 4, 0);       // garbage at j=0 meets wk==0
  const int c2m = min(wcol + 4, W_ - 4);  // garbage at j=15 meets wk==0

  const size_t chan0 = (size_t)(b * C_ + g * CG_ + chunk * NCH) * HW_;
  const float* xc = x + chan0;
  float* ob = out + chan0 + (size_t)h * W_ + wcol;

  for (int c = 0; c < NCH; ++c) {
    const float* xp = xc + (size_t)c * HW_;
    alignas(16) float acc[4] = {0.f, 0.f, 0.f, 0.f};
#pragma unroll
    for (int di = 0; di < 5; ++di) {
      alignas(16) float xr[12];
      const float* rp = xp + rowoff[di];
      *(float4*)&xr[0] = *(const float4*)(rp + c0m);
      *(float4*)&xr[4] = *(const float4*)(rp + wcol);
      *(float4*)&xr[8] = *(const float4*)(rp + c2m);
      // xr[idx] holds col (wcol-4+idx); valid taps idx = 2+t+dj in [2,9];
      // boundary-lane garbage only ever meets wk==0.
#pragma unroll
      for (int dj = 0; dj < 5; ++dj) {
        const int k = di * 5 + dj;
#pragma unroll
        for (int t = 0; t < 4; ++t) {
          acc[t] = fmaf(xr[2 + t + dj], wk[k][t], acc[t]);
        }
      }
    }
    *(float4*)(ob + (size_t)c * HW_) = *(const float4*)acc;
  }
}

extern "C" void kernel_launch(void* const* d_in, const int* in_sizes, int n_in,
                              void* d_out, int out_size, void* d_ws,
                              size_t ws_size, hipStream_t stream) {
  const float* x = (const float*)d_in[0];
  const float* w = (const float*)d_in[1];
  float* out = (float*)d_out;
  // grid: B*G * 4 bands * 4 channel-chunks = 1024 blocks of 256 threads
  ska_kernel<<<dim3(1024), dim3(256), 0, stream>>>(x, w, out);
}

// Round 5
// 125.961 us; speedup vs baseline: 2.5407x; 1.0776x over previous
//
#include <hip/hip_runtime.h>
#include <stdint.h>

// SKA: per-pixel dynamic depthwise 5x5 conv
// x: [B=8, C=256, H=64, W=64] f32
// w: [B=8, G=8, K2=25, H=64, W=64] f32
// out[b,c,h,w] = sum_k x[b,c,h+k/5-2,w+k%5-2] * w[b,g,k,h,w], g = c/32
//
// Design E (round 5): TCP/L1 vector-memory path is the serialized resource
// (round 2->4: 2x TLP gave zero speedup, VALU ~10%, all pipes idle).
// Move x taps to the LDS pipe:
//  - per channel, stage the 20x64 row window into LDS with
//    __builtin_amdgcn_global_load_lds width=16 (5 wave-instrs vs ~60 f4
//    VMEM loads), double-buffered 2 x 5KB.
//  - taps become 8B LDS reads (ds_read2_b64 fusion), separate pipe from TCP.
//  - guards zero-initialized: boundary garbage must be finite since
//    garbage * wk==0 would be NaN if guard bytes were NaN-patterned.
//  - weights stay as round 2 (25 f4 global loads once per block, masked).
// Round-3 lesson kept: static indexing only, no pointer-taking helpers,
// __launch_bounds__(256,2); watch WRITE_SIZE==32.8MB as the no-spill tripwire.

#define B_ 8
#define C_ 256
#define G_ 8
#define CG_ 32
#define H_ 64
#define W_ 64
#define K2_ 25
#define HW_ (H_ * W_)
#define NCH 8    // channels per block (CG_/4)
#define ROWS 16  // output rows per block band

// LDS layout in floats: [guard 4][buf0 1280][guard 4][buf1 1280][guard 4]
#define BUF0F 4
#define BUF1F 1288
#define LDSF 2572

__global__ __launch_bounds__(256, 2) void ska_kernel(
    const float* __restrict__ x, const float* __restrict__ w,
    float* __restrict__ out) {
  __shared__ float lds[LDSF];
  const int tid = threadIdx.x;
  const int j = tid & 15;    // column quad: cols 4j..4j+3
  const int r = tid >> 4;    // output row within band (0..15)
  const int lane = tid & 63;
  const int wv = tid >> 6;   // wave id 0..3
  const int blk = blockIdx.x;  // 1024 blocks
  const int chunk = blk & 3;
  const int band = (blk >> 2) & 3;
  const int g = (blk >> 4) & 7;
  const int b = blk >> 7;
  const int h0 = band * ROWS;
  const int h = h0 + r;
  const int wcol = j * 4;

  // ---- 25 per-pixel weight quads, OOB masks folded in (branch-free) ----
  float wk[K2_][4];
  const float* wb =
      w + (size_t)(b * G_ + g) * K2_ * HW_ + (size_t)h * W_ + wcol;
#pragma unroll
  for (int k = 0; k < K2_; ++k) {
    const int di = k / 5 - 2;
    const int dj = k % 5 - 2;
    const int hh = h + di;
    const bool rowok = (unsigned)hh < (unsigned)H_;
    const float4 wq = *(const float4*)(wb + (size_t)k * HW_);
#pragma unroll
    for (int t = 0; t < 4; ++t) {
      const int cc = wcol + t + dj;
      const bool ok = rowok && ((unsigned)cc < (unsigned)W_);
      wk[k][t] = ok ? ((const float*)&wq)[t] : 0.0f;
    }
  }

  // ---- zero the guard floats (finite garbage for masked boundary taps) ----
  if (tid < 4) lds[tid] = 0.0f;
  else if (tid < 8) lds[1284 + (tid - 4)] = 0.0f;
  else if (tid < 12) lds[2568 + (tid - 8)] = 0.0f;

  // ---- staging lane constants: LDS row lr <-> x row clamp(h0-2+lr) ----
  const int lcol = (lane & 15) * 4;
  const int lr0 = wv * 4 + (lane >> 4);            // rows 0..15 (4 waves)
  const int lr1 = 16 + (lane >> 4);                // rows 16..19 (wave 0 only)
  const int srow0 = min(max(h0 - 2 + lr0, 0), H_ - 1);
  const int srow1 = min(max(h0 - 2 + lr1, 0), H_ - 1);

  const size_t chan0 = (size_t)(b * C_ + g * CG_ + chunk * NCH) * HW_;
  const float* xc = x + chan0;
  float* ob = out + chan0 + (size_t)h * W_ + wcol;

  // ---- stage channel 0 into buf0 ----
  {
    const float* s0 = xc + srow0 * W_ + lcol;
    float* d0 = &lds[BUF0F + wv * 256];  // wave-uniform base; lane l -> +16B*l
    __builtin_amdgcn_global_load_lds(
        (const __attribute__((address_space(1))) void*)s0,
        (__attribute__((address_space(3))) void*)d0, 16, 0, 0);
    if (wv == 0) {
      const float* s1 = xc + srow1 * W_ + lcol;
      float* d1 = &lds[BUF0F + 1024];
      __builtin_amdgcn_global_load_lds(
          (const __attribute__((address_space(1))) void*)s1,
          (__attribute__((address_space(3))) void*)d1, 16, 0, 0);
    }
  }
  __syncthreads();

  for (int c = 0; c < NCH; ++c) {
    // prefetch next channel into the other buffer (overlaps with compute;
    // the end-of-iter __syncthreads drains it)
    if (c + 1 < NCH) {
      const float* xp1 = xc + (size_t)(c + 1) * HW_;
      const int bb1 = ((c + 1) & 1) ? BUF1F : BUF0F;
      const float* s0 = xp1 + srow0 * W_ + lcol;
      float* d0 = &lds[bb1 + wv * 256];
      __builtin_amdgcn_global_load_lds(
          (const __attribute__((address_space(1))) void*)s0,
          (__attribute__((address_space(3))) void*)d0, 16, 0, 0);
      if (wv == 0) {
        const float* s1 = xp1 + srow1 * W_ + lcol;
        float* d1 = &lds[bb1 + 1024];
        __builtin_amdgcn_global_load_lds(
            (const __attribute__((address_space(1))) void*)s1,
            (__attribute__((address_space(3))) void*)d1, 16, 0, 0);
      }
    }

    const int bb = (c & 1) ? BUF1F : BUF0F;
    alignas(16) float acc[4] = {0.f, 0.f, 0.f, 0.f};
#pragma unroll
    for (int di = 0; di < 5; ++di) {
      // LDS row r+di covers x row h+di-2 (clamped); cols wcol-2..wcol+5
      const float* rp = &lds[bb + (r + di) * 64 + wcol - 2];  // 8B aligned
      alignas(16) float xr[8];
      *(float2*)&xr[0] = *(const float2*)(rp + 0);
      *(float2*)&xr[2] = *(const float2*)(rp + 2);
      *(float2*)&xr[4] = *(const float2*)(rp + 4);
      *(float2*)&xr[6] = *(const float2*)(rp + 6);
#pragma unroll
      for (int dj = 0; dj < 5; ++dj) {
        const int k = di * 5 + dj;
#pragma unroll
        for (int t = 0; t < 4; ++t) {
          acc[t] = fmaf(xr[t + dj], wk[k][t], acc[t]);
        }
      }
    }
    *(float4*)(ob + (size_t)c * HW_) = *(const float4*)acc;
    if (c + 1 < NCH) __syncthreads();
  }
}

extern "C" void kernel_launch(void* const* d_in, const int* in_sizes, int n_in,
                              void* d_out, int out_size, void* d_ws,
                              size_t ws_size, hipStream_t stream) {
  const float* x = (const float*)d_in[0];
  const float* w = (const float*)d_in[1];
  float* out = (float*)d_out;
  // grid: B*G * 4 bands * 4 channel-chunks = 1024 blocks of 256 threads
  ska_kernel<<<dim3(1024), dim3(256), 0, stream>>>(x, w, out);
}

// Round 7
// 114.972 us; speedup vs baseline: 2.7835x; 1.0956x over previous
//
#include <hip/hip_runtime.h>

// SKA: per-pixel dynamic depthwise 5x5 conv
// x: [B=8, C=256, H=64, W=64] f32
// w: [B=8, G=8, K2=25, H=64, W=64] f32
// out[b,c,h,w] = sum_k x[b,c,h+k/5-2,w+k%5-2] * w[b,g,k,h,w], g = c/32
//
// Design F2 (round 7): design F + wave_barrier fix.
// Round-6 failure: cross-lane LDS exchange inside a wave with no sync ->
// compiler hoisted ds_reads above ds_writes (per-thread they don't alias).
// HW is in-order for DS within a wave; only the COMPILER needs pinning:
// __builtin_amdgcn_wave_barrier() = zero-instruction scheduling fence
// (no vmcnt drain, unlike __syncthreads -> keeps the async pipeline).
// Two per iter: ...reads(c-1) |WB| writes(c) |WB| reads(c)... also orders
// buffer reuse at c+2.
//  - wave owns 4 output rows x 64 cols; stages 8x64 window per channel via
//    2 float4 VGPR loads -> padded LDS (pitch 66 words = exactly 4
//    accesses/bank per ds_read_b64 = conflict floor).
//  - global->VGPR staging is register-explicit: compiler emits fine
//    vmcnt(N), next channel's loads stay in flight (no barrier drain).
//  - guards/pads zeroed once (masked-tap garbage must stay finite).
// SROA lesson (round 3): static indexing only, no pointer-taking helpers.
// Tripwire: WRITE_SIZE must stay 32768 KB (no scratch spill).

#define B_ 8
#define C_ 256
#define G_ 8
#define CG_ 32
#define H_ 64
#define W_ 64
#define K2_ 25
#define HW_ (H_ * W_)
#define NCH 8      // channels per block
#define PITCH 66   // padded LDS row pitch in words (conflict-free)
#define BUFW 544   // words per buffer: 2 guard + 8*66 = 530, rounded up
#define WAVEW (2 * BUFW)

__global__ __launch_bounds__(256, 2) void ska_kernel(
    const float* __restrict__ x, const float* __restrict__ w,
    float* __restrict__ out) {
  __shared__ float lds[4 * WAVEW];
  const int tid = threadIdx.x;
  const int lane = tid & 63;
  const int wv = tid >> 6;
  const int j = lane & 15;  // column quad: cols 4j..4j+3
  const int r = lane >> 4;  // row within wave tile (0..3)
  const int blk = blockIdx.x;  // 1024 blocks
  const int chunk = blk & 3;
  const int band = (blk >> 2) & 3;
  const int g = (blk >> 4) & 7;
  const int b = blk >> 7;
  const int h0w = band * 16 + wv * 4;  // wave's first output row
  const int h = h0w + r;
  const int wcol = j * 4;
  const int wbase = wv * WAVEW;

  // ---- zero guards (words 0,1) + row pads (2+rr*66+{64,65}) of both bufs ----
  if (lane < 18) {
    int idx;
    if (lane < 2) idx = lane;
    else idx = 2 + ((lane - 2) >> 1) * PITCH + 64 + ((lane - 2) & 1);
    lds[wbase + idx] = 0.0f;
    lds[wbase + BUFW + idx] = 0.0f;
  }

  // ---- 25 per-pixel weight quads, OOB masks folded in (branch-free) ----
  float wk[K2_][4];
  const float* wb =
      w + (size_t)(b * G_ + g) * K2_ * HW_ + (size_t)h * W_ + wcol;
#pragma unroll
  for (int k = 0; k < K2_; ++k) {
    const int di = k / 5 - 2;
    const int dj = k % 5 - 2;
    const int hh = h + di;
    const bool rowok = (unsigned)hh < (unsigned)H_;
    const float4 wq = *(const float4*)(wb + (size_t)k * HW_);
#pragma unroll
    for (int t = 0; t < 4; ++t) {
      const int cc = wcol + t + dj;
      const bool ok = rowok && ((unsigned)cc < (unsigned)W_);
      wk[k][t] = ok ? ((const float*)&wq)[t] : 0.0f;
    }
  }

  // ---- staging constants: lane -> (window rows sr, sr+4; col quad scol) ----
  const int scol = (lane & 15) * 4;
  const int sr = lane >> 4;  // 0..3
  const int srow0 = min(max(h0w - 2 + sr, 0), H_ - 1);
  const int srow1 = min(max(h0w + 2 + sr, 0), H_ - 1);
  const int woff0 = wbase + 2 + sr * PITCH + scol;
  const int woff1 = wbase + 2 + (4 + sr) * PITCH + scol;

  const size_t chan0 = (size_t)(b * C_ + g * CG_ + chunk * NCH) * HW_;
  const float* xc = x + chan0;
  float* ob = out + chan0 + (size_t)h * W_ + wcol;

  // ---- prime the pipeline: channel 0 window in VGPRs ----
  float4 q0 = *(const float4*)(xc + srow0 * W_ + scol);
  float4 q1 = *(const float4*)(xc + srow1 * W_ + scol);

  for (int c = 0; c < NCH; ++c) {
    // issue next channel's loads (stay in flight across this iter's work)
    const int cn = min(c + 1, NCH - 1);
    const float* xn = xc + (size_t)cn * HW_;
    const float4 p0 = *(const float4*)(xn + srow0 * W_ + scol);
    const float4 p1 = *(const float4*)(xn + srow1 * W_ + scol);

    // write current window to this wave's buffer (wave-in-order DS).
    // wave_barrier: pin compiler order vs prior iter's reads (buffer reuse)
    __builtin_amdgcn_wave_barrier();
    const int bo = (c & 1) * BUFW;
    *(float2*)&lds[woff0 + bo] = make_float2(q0.x, q0.y);
    *(float2*)&lds[woff0 + bo + 2] = make_float2(q0.z, q0.w);
    *(float2*)&lds[woff1 + bo] = make_float2(q1.x, q1.y);
    *(float2*)&lds[woff1 + bo + 2] = make_float2(q1.z, q1.w);
    // wave_barrier: reads below must not be hoisted above the writes
    __builtin_amdgcn_wave_barrier();

    alignas(16) float acc[4] = {0.f, 0.f, 0.f, 0.f};
#pragma unroll
    for (int di = 0; di < 5; ++di) {
      // window row r+di, cols wcol-2..wcol+5 (guards/pads cover edges)
      const int base = wbase + bo + (r + di) * PITCH + wcol;  // data -2 offset
      alignas(16) float xr[8];
      *(float2*)&xr[0] = *(const float2*)&lds[base];
      *(float2*)&xr[2] = *(const float2*)&lds[base + 2];
      *(float2*)&xr[4] = *(const float2*)&lds[base + 4];
      *(float2*)&xr[6] = *(const float2*)&lds[base + 6];
#pragma unroll
      for (int dj = 0; dj < 5; ++dj) {
        const int k = di * 5 + dj;
#pragma unroll
        for (int t = 0; t < 4; ++t) {
          acc[t] = fmaf(xr[t + dj], wk[k][t], acc[t]);
        }
      }
    }
    *(float4*)(ob + (size_t)c * HW_) = *(const float4*)acc;
    q0 = p0;
    q1 = p1;
  }
}

extern "C" void kernel_launch(void* const* d_in, const int* in_sizes, int n_in,
                              void* d_out, int out_size, void* d_ws,
                              size_t ws_size, hipStream_t stream) {
  const float* x = (const float*)d_in[0];
  const float* w = (const float*)d_in[1];
  float* out = (float*)d_out;
  // grid: B*G * 4 bands * 4 channel-chunks = 1024 blocks of 256 threads
  ska_kernel<<<dim3(1024), dim3(256), 0, stream>>>(x, w, out);
}